// Round 2
// baseline (521.270 us; speedup 1.0000x reference)
//
#include <hip/hip_runtime.h>
#include <math.h>

#define K_CODES 512
#define DIM 64
#define ROWS_PER_BLOCK 128   // old kernel: 256 threads, 2 k-halves per row

// ---------------------------------------------------------------------------
// Exact-arithmetic helpers (bit-match the verified round-1/2 kernels).
// ---------------------------------------------------------------------------
__device__ __forceinline__ float np_pairwise_sumsq(const float* v) {
#pragma clang fp contract(off)
    float p[DIM];
#pragma unroll
    for (int j = 0; j < DIM; ++j) p[j] = v[j] * v[j];
    float r[8];
#pragma unroll
    for (int a = 0; a < 8; ++a) r[a] = p[a];
#pragma unroll
    for (int i = 8; i < DIM; i += 8) {
#pragma unroll
        for (int a = 0; a < 8; ++a) r[a] = r[a] + p[i + a];
    }
    return ((r[0] + r[1]) + (r[2] + r[3])) + ((r[4] + r[5]) + (r[6] + r[7]));
}

// 8-accumulator fmaf dot + tree combine — IDENTICAL arithmetic to the
// verified kernels (matches np argmin exactly). Do not alter.
__device__ __forceinline__ float np_dot8acc(const float* zr, const float* ck) {
#pragma clang fp contract(off)
    float a0 = 0.f, a1 = 0.f, a2 = 0.f, a3 = 0.f;
    float a4 = 0.f, a5 = 0.f, a6 = 0.f, a7 = 0.f;
#pragma unroll
    for (int j = 0; j < DIM; j += 8) {
        a0 = fmaf(zr[j + 0], ck[j + 0], a0);
        a1 = fmaf(zr[j + 1], ck[j + 1], a1);
        a2 = fmaf(zr[j + 2], ck[j + 2], a2);
        a3 = fmaf(zr[j + 3], ck[j + 3], a3);
        a4 = fmaf(zr[j + 4], ck[j + 4], a4);
        a5 = fmaf(zr[j + 5], ck[j + 5], a5);
        a6 = fmaf(zr[j + 6], ck[j + 6], a6);
        a7 = fmaf(zr[j + 7], ck[j + 7], a7);
    }
    return ((a0 + a1) + (a2 + a3)) + ((a4 + a5) + (a6 + a7));
}

// ---------------------------------------------------------------------------
// OLD KERNEL (verified, 176 us) — kept as dispatch fallback if ws too small.
// ---------------------------------------------------------------------------
__global__ __launch_bounds__(256, 4) void vq_argmin_gather(
    const float* __restrict__ z, const float* __restrict__ cb,
    float* __restrict__ out, int n_rows) {
#pragma clang fp contract(off)
    __shared__ float esq_lds[K_CODES];
    __shared__ float red_d[ROWS_PER_BLOCK];
    __shared__ int   red_b[ROWS_PER_BLOCK];
    __shared__ int   best_lds[ROWS_PER_BLOCK];

    const int t = threadIdx.x;
    const int tr  = t & (ROWS_PER_BLOCK - 1);
    const int row = blockIdx.x * ROWS_PER_BLOCK + tr;
    const int k0 = __builtin_amdgcn_readfirstlane((t >> 7) << 8);

    float zr[DIM];
    const float4* zp = (const float4*)(z + (size_t)row * DIM);
#pragma unroll
    for (int j = 0; j < DIM / 4; ++j) {
        float4 v = zp[j];
        zr[4 * j + 0] = v.x; zr[4 * j + 1] = v.y;
        zr[4 * j + 2] = v.z; zr[4 * j + 3] = v.w;
    }
#pragma unroll
    for (int j = 0; j < DIM; ++j) { asm volatile("" : "+v"(zr[j])); }

    for (int c = t; c < K_CODES; c += 256)
        esq_lds[c] = np_pairwise_sumsq(cb + (size_t)c * DIM);
    __syncthreads();

    const float zsq = np_pairwise_sumsq(zr);
    float dmin = INFINITY;
    int best = k0;
    const float* __restrict__ cbase = cb + (size_t)k0 * DIM;
#pragma unroll 2
    for (int kk = 0; kk < K_CODES / 2; ++kk) {
        const float dot = np_dot8acc(zr, cbase + (size_t)kk * DIM);
        const float tkv = zsq + esq_lds[k0 + kk];
        const float m = 2.0f * dot;
        const float d = tkv - m;
        if (d < dmin) { dmin = d; best = k0 + kk; }
    }
    if (t >= ROWS_PER_BLOCK) { red_d[tr] = dmin; red_b[tr] = best; }
    __syncthreads();
    if (t < ROWS_PER_BLOCK) {
        int b = (red_d[tr] < dmin) ? red_b[tr] : best;
        best_lds[tr] = b;
    }
    __syncthreads();

    const float4* cb4 = (const float4*)cb;
    float4* o = (float4*)out;
    const size_t out1_off = (size_t)n_rows * (DIM / 4);
    const size_t grow = (size_t)blockIdx.x * ROWS_PER_BLOCK * (DIM / 4);
#pragma unroll
    for (int i = t; i < ROWS_PER_BLOCK * (DIM / 4); i += 256) {
        const int r = i >> 4;
        const int j = i & 15;
        const float4 v = cb4[(size_t)best_lds[r] * (DIM / 4) + j];
        const size_t g = grow + (size_t)r * (DIM / 4) + j;
        o[g] = v;
        o[g + out1_off] = v;
    }
}

// ---------------------------------------------------------------------------
// NEW PATH: split-bf16 MFMA with exact-emulation fallback for ambiguous rows.
// ---------------------------------------------------------------------------
typedef __bf16 bfx8 __attribute__((ext_vector_type(8)));
typedef float  f32x4 __attribute__((ext_vector_type(4)));

// Gap threshold: worst-case |approx_score - reference_score| relative
// deviation between two codes is ~4e-5 (dropped lo*lo + split residuals +
// fp32 accumulation-order noise + reference's own zsq-add rounding).
// 2e-4 gives 5x margin; ~2-3% of rows take the bit-exact path.
#define EPS_GAP 2.0e-4f

// fp32 -> (hi bf16, lo bf16). hi = round-half-up to bf16 (|x-hi| <= 2^-9|x|),
// x - hi is EXACT in fp32 (Sterbenz), lo = rounded residual
// (|residual - lo| <= 2^-18|x|).
__device__ __forceinline__ void split_bf16(float x, unsigned short& h, unsigned short& l) {
    unsigned int xb = __float_as_uint(x);
    unsigned int hb = (xb + 0x8000u) & 0xffff0000u;
    h = (unsigned short)(hb >> 16);
    float lf = x - __uint_as_float(hb);
    l = (unsigned short)((__float_as_uint(lf) + 0x8000u) >> 16);
}

// Prep: pack codebook into MFMA B-fragment order (hi/lo) + np-order esq.
// Fragment slot id = (tile*2 + kstep)*64 + lane; element j of lane l is
// cb[tile*16 + (l&15)][kstep*32 + (l>>4)*8 + j].  4096 slots, 16B each.
// (B frag for 16x16x32: col = lane&15, k = (lane>>4)*8 + j — the layout the
// ref-verified m92/m97 GEMMs load as 8 contiguous bf16 per lane.)
__global__ void vq_prep(const float* __restrict__ cb,
                        unsigned short* __restrict__ wh,
                        unsigned short* __restrict__ wl,
                        float* __restrict__ esq) {
    const int id = blockIdx.x * 256 + threadIdx.x;      // 0..4095
    const int l = id & 63;
    const int s = (id >> 6) & 1;
    const int t = id >> 7;
    const int code = t * 16 + (l & 15);
    const int d0 = s * 32 + (l >> 4) * 8;
    const float* p = cb + (size_t)code * DIM + d0;
    float4 v0 = *(const float4*)p;
    float4 v1 = *(const float4*)(p + 4);
    float f[8] = {v0.x, v0.y, v0.z, v0.w, v1.x, v1.y, v1.z, v1.w};
    union { unsigned short u[8]; uint4 q; } H, L;
#pragma unroll
    for (int j = 0; j < 8; ++j) split_bf16(f[j], H.u[j], L.u[j]);
    *(uint4*)(wh + (size_t)id * 8) = H.q;
    *(uint4*)(wl + (size_t)id * 8) = L.q;
    if (id < K_CODES) esq[id] = np_pairwise_sumsq(cb + (size_t)id * DIM);
}

__device__ __forceinline__ bfx8 ld_bfx8(const unsigned short* base, int slot) {
    return *reinterpret_cast<const bfx8*>(base + (size_t)slot * 8);
}

// 256 threads = 4 waves; 32 rows/wave -> 128 rows/block; grid = n_rows/128.
// Per wave: A-frags (z rows, hi+lo, 2 k-steps) live in VGPRs; loop 32 code
// tiles; 12 MFMA/tile (2 rowsets x 2 ksteps x {hh, hl, lh}); per-lane running
// (best, second-best); 16-lane shfl-xor reduce; ambiguous rows re-solved with
// the bit-exact VALU path.
// launch_bounds(256,2): VGPR budget ~150 (A 32 + B cur/next 64 + state 24 +
// acc 8 + addr) exceeds the 128 cap that (256,4) imposes -> spills. 2 waves/EU
// (8 waves/CU) is enough for this MFMA-dense, L2-resident-B loop.
__global__ __launch_bounds__(256, 2) void vq_mfma(
    const float* __restrict__ z, const float* __restrict__ cb,
    const unsigned short* __restrict__ wh, const unsigned short* __restrict__ wl,
    const float* __restrict__ esq_g,
    float* __restrict__ out, int n_rows) {
    __shared__ float esq_lds[K_CODES];
    __shared__ int   best_lds[128];
    __shared__ int   flaglist[128];
    __shared__ int   nflag;

    const int t = threadIdx.x;
    const int wave = t >> 6;
    const int lane = t & 63;
    const int lg = lane >> 4;      // k-group / D-row group
    const int lr = lane & 15;      // A row within set / D col (code)
    const int rb = blockIdx.x * 128;
    const int wrb = rb + wave * 32;

    if (t == 0) nflag = 0;
    for (int i = t; i < K_CODES; i += 256) esq_lds[i] = esq_g[i];

    // A fragments: z rows -> hi/lo bf16, layout row=lane&15,
    // k = kstep*32 + (lane>>4)*8 + j. Loaded once, kept in VGPRs.
    bfx8 a_hi[2][2], a_lo[2][2];
#pragma unroll
    for (int RS = 0; RS < 2; ++RS) {
#pragma unroll
        for (int s = 0; s < 2; ++s) {
            const float* zp = z + (size_t)(wrb + RS * 16 + lr) * DIM + s * 32 + lg * 8;
            float4 v0 = *(const float4*)zp;
            float4 v1 = *(const float4*)(zp + 4);
            float f[8] = {v0.x, v0.y, v0.z, v0.w, v1.x, v1.y, v1.z, v1.w};
            union { unsigned short u[8]; bfx8 b; } H, L;
#pragma unroll
            for (int j = 0; j < 8; ++j) split_bf16(f[j], H.u[j], L.u[j]);
            a_hi[RS][s] = H.b;
            a_lo[RS][s] = L.b;
        }
    }
    __syncthreads();   // esq_lds + nflag ready

    float b1[2][4], b2[2][4];
    int   k1[2][4];
#pragma unroll
    for (int RS = 0; RS < 2; ++RS)
#pragma unroll
        for (int i = 0; i < 4; ++i) { b1[RS][i] = INFINITY; b2[RS][i] = INFINITY; k1[RS][i] = 0; }

    // Software-pipelined B-fragment loads (L2-resident, lane-linear dwordx4).
    bfx8 bh0 = ld_bfx8(wh, 0 * 64 + lane), bh1 = ld_bfx8(wh, 1 * 64 + lane);
    bfx8 bl0 = ld_bfx8(wl, 0 * 64 + lane), bl1 = ld_bfx8(wl, 1 * 64 + lane);

    for (int tt = 0; tt < 32; ++tt) {
        f32x4 acc0 = {0.f, 0.f, 0.f, 0.f};
        f32x4 acc1 = {0.f, 0.f, 0.f, 0.f};
        // rowset 0
        acc0 = __builtin_amdgcn_mfma_f32_16x16x32_bf16(a_hi[0][0], bh0, acc0, 0, 0, 0);
        acc0 = __builtin_amdgcn_mfma_f32_16x16x32_bf16(a_hi[0][1], bh1, acc0, 0, 0, 0);
        acc0 = __builtin_amdgcn_mfma_f32_16x16x32_bf16(a_hi[0][0], bl0, acc0, 0, 0, 0);
        acc0 = __builtin_amdgcn_mfma_f32_16x16x32_bf16(a_hi[0][1], bl1, acc0, 0, 0, 0);
        acc0 = __builtin_amdgcn_mfma_f32_16x16x32_bf16(a_lo[0][0], bh0, acc0, 0, 0, 0);
        acc0 = __builtin_amdgcn_mfma_f32_16x16x32_bf16(a_lo[0][1], bh1, acc0, 0, 0, 0);
        // rowset 1
        acc1 = __builtin_amdgcn_mfma_f32_16x16x32_bf16(a_hi[1][0], bh0, acc1, 0, 0, 0);
        acc1 = __builtin_amdgcn_mfma_f32_16x16x32_bf16(a_hi[1][1], bh1, acc1, 0, 0, 0);
        acc1 = __builtin_amdgcn_mfma_f32_16x16x32_bf16(a_hi[1][0], bl0, acc1, 0, 0, 0);
        acc1 = __builtin_amdgcn_mfma_f32_16x16x32_bf16(a_hi[1][1], bl1, acc1, 0, 0, 0);
        acc1 = __builtin_amdgcn_mfma_f32_16x16x32_bf16(a_lo[1][0], bh0, acc1, 0, 0, 0);
        acc1 = __builtin_amdgcn_mfma_f32_16x16x32_bf16(a_lo[1][1], bh1, acc1, 0, 0, 0);

        // prefetch next tile's B frags under the MFMA latency
        const int nt = (tt + 1) & 31;
        bfx8 nh0 = ld_bfx8(wh, (nt * 2 + 0) * 64 + lane);
        bfx8 nh1 = ld_bfx8(wh, (nt * 2 + 1) * 64 + lane);
        bfx8 nl0 = ld_bfx8(wl, (nt * 2 + 0) * 64 + lane);
        bfx8 nl1 = ld_bfx8(wl, (nt * 2 + 1) * 64 + lane);

        const float ev = esq_lds[tt * 16 + lr];
        const int   kk = tt * 16 + lr;
#pragma unroll
        for (int i = 0; i < 4; ++i) {
            {
                float s0 = fmaf(-2.0f, acc0[i], ev);   // row-constant zsq dropped
                bool c = s0 < b1[0][i];
                float nb2 = c ? b1[0][i] : fminf(b2[0][i], s0);
                b1[0][i] = c ? s0 : b1[0][i];
                k1[0][i] = c ? kk : k1[0][i];
                b2[0][i] = nb2;
            }
            {
                float s1 = fmaf(-2.0f, acc1[i], ev);
                bool c = s1 < b1[1][i];
                float nb2 = c ? b1[1][i] : fminf(b2[1][i], s1);
                b1[1][i] = c ? s1 : b1[1][i];
                k1[1][i] = c ? kk : k1[1][i];
                b2[1][i] = nb2;
            }
        }
        bh0 = nh0; bh1 = nh1; bl0 = nl0; bl1 = nl1;
    }

    // Reduce (b1,k1,b2) across the 16 lanes of each D-row group.
#pragma unroll
    for (int m = 1; m <= 8; m <<= 1) {
#pragma unroll
        for (int RS = 0; RS < 2; ++RS) {
#pragma unroll
            for (int i = 0; i < 4; ++i) {
                float ob1 = __shfl_xor(b1[RS][i], m);
                int   ok1 = __shfl_xor(k1[RS][i], m);
                float ob2 = __shfl_xor(b2[RS][i], m);
                float nb2 = fminf(fmaxf(b1[RS][i], ob1), fminf(b2[RS][i], ob2));
                bool take = (ob1 < b1[RS][i]) || (ob1 == b1[RS][i] && ok1 < k1[RS][i]);
                b1[RS][i] = take ? ob1 : b1[RS][i];
                k1[RS][i] = take ? ok1 : k1[RS][i];
                b2[RS][i] = nb2;
            }
        }
    }

    // Publish results; flag rows whose top-2 gap is inside the error bound.
    // D layout (m89/m91-verified): col=lane&15 (code), row=(lane>>4)*4+reg.
    if (lr == 0) {
#pragma unroll
        for (int RS = 0; RS < 2; ++RS) {
#pragma unroll
            for (int i = 0; i < 4; ++i) {
                const int rl = wave * 32 + RS * 16 + lg * 4 + i;
                best_lds[rl] = k1[RS][i];
                if (b2[RS][i] - b1[RS][i] <= EPS_GAP) {
                    int p = atomicAdd(&nflag, 1);
                    flaglist[p] = rl;
                }
            }
        }
    }
    __syncthreads();

    // Exact fallback: wave-parallel (8 codes/lane), bit-identical arithmetic.
    const int nf = nflag;
    for (int fi = wave; fi < nf; fi += 4) {
        const int rl = flaglist[fi];
        const float* zp = z + (size_t)(rb + rl) * DIM;
        float zr[DIM];
#pragma unroll
        for (int j = 0; j < DIM / 4; ++j) {
            float4 v = ((const float4*)zp)[j];
            zr[4 * j + 0] = v.x; zr[4 * j + 1] = v.y;
            zr[4 * j + 2] = v.z; zr[4 * j + 3] = v.w;
        }
        const float zsq = np_pairwise_sumsq(zr);
        float dmin = INFINITY;
        int bk = lane * 8;
        const float* cbase = cb + (size_t)(lane * 8) * DIM;
#pragma unroll
        for (int c = 0; c < 8; ++c) {
#pragma clang fp contract(off)
            const float dot = np_dot8acc(zr, cbase + (size_t)c * DIM);
            const float tkv = zsq + esq_lds[lane * 8 + c];
            const float m2 = 2.0f * dot;
            const float d = tkv - m2;
            if (d < dmin) { dmin = d; bk = lane * 8 + c; }
        }
#pragma unroll
        for (int m = 1; m <= 32; m <<= 1) {
            float od = __shfl_xor(dmin, m);
            int   ob = __shfl_xor(bk, m);
            bool take = (od < dmin) || (od == dmin && ob < bk);
            dmin = take ? od : dmin;
            bk = take ? ob : bk;
        }
        if (lane == 0) best_lds[rl] = bk;
    }
    __syncthreads();

    // Block-cooperative coalesced gather + dual write (identical to old path).
    const float4* cb4 = (const float4*)cb;
    float4* o = (float4*)out;
    const size_t out1_off = (size_t)n_rows * (DIM / 4);
    const size_t grow = (size_t)blockIdx.x * 128 * (DIM / 4);
#pragma unroll
    for (int i = t; i < 128 * (DIM / 4); i += 256) {
        const int r = i >> 4;
        const int j = i & 15;
        const float4 v = cb4[(size_t)best_lds[r] * (DIM / 4) + j];
        const size_t g = grow + (size_t)r * (DIM / 4) + j;
        o[g] = v;
        o[g + out1_off] = v;
    }
}

// ---------------------------------------------------------------------------
extern "C" void kernel_launch(void* const* d_in, const int* in_sizes, int n_in,
                              void* d_out, int out_size, void* d_ws, size_t ws_size,
                              hipStream_t stream) {
    const float* z  = (const float*)d_in[0];   // [N, 64] fp32
    const float* cb = (const float*)d_in[1];   // [512, 64] fp32
    float* out = (float*)d_out;                // [2 * N * 64] fp32

    const int n_rows = in_sizes[0] / DIM;      // 131072
    const int grid = n_rows / 128;             // 1024 blocks of 256

    // ws layout: cb_hi frags 64KB | cb_lo frags 64KB | esq 2KB
    const size_t WS_NEED = (size_t)K_CODES * DIM * 2 * 2 + K_CODES * 4;
    if (ws_size >= WS_NEED && (n_rows % 128) == 0) {
        unsigned short* wh = (unsigned short*)d_ws;
        unsigned short* wl = wh + (size_t)K_CODES * DIM;
        float* esq = (float*)(wl + (size_t)K_CODES * DIM);
        vq_prep<<<dim3(16), dim3(256), 0, stream>>>(cb, wh, wl, esq);
        vq_mfma<<<dim3(grid), dim3(256), 0, stream>>>(z, cb, wh, wl, esq, out, n_rows);
    } else {
        vq_argmin_gather<<<dim3(grid), dim3(256), 0, stream>>>(z, cb, out, n_rows);
    }
}